// Round 10
// baseline (1307.421 us; speedup 1.0000x reference)
//
#include <hip/hip_runtime.h>
#include <math.h>

// Problem constants
#define F_DIM 321
#define H_DIM 4200
#define T_DIM 1000
#define NBC   16      // B*C = 8*2
#define KTOP  3
#define PADV  1e-8f

// GEMM tiling
#define BM 128        // h rows per block tile
#define BN 128        // t cols per block tile
#define BK 32
#define LDA 36        // As[h][k] row stride (words)
#define LDB 132       // Bs[k][t] row stride (words)
#define NHT 33        // ceil(H_DIM / BM)
#define NKT 10        // k-tiles of 32 covering k=0..319 (tail k=320 separate)

typedef float v4f __attribute__((ext_vector_type(4)));

__device__ __forceinline__ void ins3(float v, int i,
                                     float& v0, float& v1, float& v2,
                                     int& i0, int& i1, int& i2) {
  // strict '>' keeps earlier (smaller-h) entries ahead on ties == lax.top_k
  if (v > v0)      { v2 = v1; i2 = i1; v1 = v0; i1 = i0; v0 = v; i0 = i; }
  else if (v > v1) { v2 = v1; i2 = i1; v1 = v;  i1 = i; }
  else if (v > v2) { v2 = v;  i2 = i; }
}

// K1: fused fp32 GEMM (nominee = integral_m @ mag[bc]) + running top-3 over h.
// 256 threads, 8x8 micro-tile, low-pressure inner loop (B fragments resident,
// A rows streamed, g-loop unroll 1 -> live ~110 regs). NO waves_per_eu
// attribute: r6/r7/r9 showed every occupancy hint makes the allocator pick a
// wave tier first and spill acc to fit it (51 MB/245 MB/186 MB scratch).
// Default heuristic minimizes spill; live set now genuinely fits 128.
__global__ __launch_bounds__(256)
void hi_k1_gemm_top3(const float* __restrict__ mag,
                     const float* __restrict__ im,
                     float* __restrict__ wv, int* __restrict__ wi,
                     int nsplit) {
  const int tid = threadIdx.x;
  const int tx = tid & 15;
  const int ty = tid >> 4;        // 16 row-groups of 8
  const int t0 = blockIdx.x * BN;
  const int bc = blockIdx.y;
  const int sp = blockIdx.z;
  const int ht_begin = (sp * NHT) / nsplit;
  const int ht_end   = ((sp + 1) * NHT) / nsplit;
  const int row0 = ty * 8;
  const int xsw = (ty & 3) << 2;  // A read swizzle for this thread's rows
  const int wvi = tid >> 6;       // wave index 0..3

  __shared__ __align__(16) float As[BM * LDA];  // As[h][k^swz]
  __shared__ __align__(16) float Bs[BK * LDB];  // Bs[k][t]
  // merge scratch aliases As (used only between barriers after compute)
  float* mv = As;                               // [4 waves][BN][3]
  int*   mi = (int*)(As + 4 * BN * KTOP);

  const float* magbc = mag + (size_t)bc * F_DIM * T_DIM;
  const bool tfull = (t0 + BN <= T_DIM);

  float gv0 = -INFINITY, gv1 = -INFINITY, gv2 = -INFINITY;
  int   gi0 = 0, gi1 = 0, gi2 = 0;

  for (int ht = ht_begin; ht < ht_end; ++ht) {
    const int h0 = ht * BM;
    float acc[8][8];
#pragma unroll
    for (int r = 0; r < 8; ++r)
#pragma unroll
      for (int c = 0; c < 8; ++c) acc[r][c] = 0.f;

    for (int kt = 0; kt < NKT; ++kt) {
      const int k0 = kt * BK;
      __syncthreads();   // protect As/Bs (incl. mv/mi alias) from prior phase
      // stage A: lanes run over k -> coalesced global; swizzled LDS k-group
#pragma unroll
      for (int l = 0; l < 16; ++l) {
        int e = tid + 256 * l;
        int kk = e & 31, hh = e >> 5;
        int gh = h0 + hh;
        int ksw = kk ^ (((hh >> 3) & 3) << 2);
        As[hh * LDA + ksw] = (gh < H_DIM) ? im[(size_t)gh * F_DIM + k0 + kk] : 0.f;
      }
      // stage B: vectorized float4 over t (16B-aligned: stride 1000*4, t0*4)
      if (tfull) {
#pragma unroll
        for (int l = 0; l < 4; ++l) {
          int e = tid + 256 * l;
          int tq = e & 31, kk = e >> 5;
          v4f v = *(const v4f*)(magbc + (size_t)(k0 + kk) * T_DIM + t0 + tq * 4);
          *(v4f*)(Bs + kk * LDB + tq * 4) = v;
        }
      } else {
#pragma unroll
        for (int l = 0; l < 4; ++l) {
          int e = tid + 256 * l;
          int tq = e & 31, kk = e >> 5;
          v4f v;
#pragma unroll
          for (int j = 0; j < 4; ++j) {
            int gt = t0 + tq * 4 + j;
            v[j] = (gt < T_DIM) ? magbc[(size_t)(k0 + kk) * T_DIM + gt] : 0.f;
          }
          *(v4f*)(Bs + kk * LDB + tq * 4) = v;
        }
      }
      __syncthreads();
      // compute: 8 groups of 4 k; B fragments resident, A rows streamed
#pragma unroll 1
      for (int g = 0; g < 8; ++g) {
        v4f Bv[8];
#pragma unroll
        for (int kk = 0; kk < 4; ++kk) {
          Bv[kk * 2]     = *(const v4f*)(Bs + (g * 4 + kk) * LDB + tx * 4);
          Bv[kk * 2 + 1] = *(const v4f*)(Bs + (g * 4 + kk) * LDB + 64 + tx * 4);
        }
#pragma unroll
        for (int r = 0; r < 8; ++r) {
          const v4f Ar = *(const v4f*)(As + (row0 + r) * LDA + ((g * 4) ^ xsw));
#pragma unroll
          for (int kk = 0; kk < 4; ++kk)
#pragma unroll
            for (int c = 0; c < 4; ++c) {
              acc[r][c]     = fmaf(Ar[kk], Bv[kk * 2][c],     acc[r][c]);
              acc[r][c + 4] = fmaf(Ar[kk], Bv[kk * 2 + 1][c], acc[r][c + 4]);
            }
        }
      }
    }
    // K tail: k = 320 (single column), straight from global (L2-resident)
    {
      float bt[8];
#pragma unroll
      for (int c = 0; c < 8; ++c) {
        int gt = t0 + ((c < 4) ? (tx * 4 + c) : (64 + tx * 4 + c - 4));
        bt[c] = (gt < T_DIM) ? magbc[(size_t)(F_DIM - 1) * T_DIM + gt] : 0.f;
      }
#pragma unroll
      for (int r = 0; r < 8; ++r) {
        int gh = h0 + row0 + r;
        float a = (gh < H_DIM) ? im[(size_t)gh * F_DIM + (F_DIM - 1)] : 0.f;
#pragma unroll
        for (int c = 0; c < 8; ++c) acc[r][c] = fmaf(a, bt[c], acc[r][c]);
      }
    }

    __syncthreads();   // all waves done reading As before aliasing as mv/mi

    // per-column top-3 over own 8 rows (h ascending), then merge the 4
    // ty-bands in each wave (shfl_down 16 then 32 keeps ascending-h order)
#pragma unroll
    for (int c = 0; c < 8; ++c) {
      const int col = (c < 4) ? (tx * 4 + c) : (64 + tx * 4 + c - 4);
      float v0 = -INFINITY, v1 = -INFINITY, v2 = -INFINITY;
      int   i0 = 0, i1 = 0, i2 = 0;
#pragma unroll
      for (int r = 0; r < 8; ++r) {
        int gh = h0 + row0 + r;
        float v = (gh < H_DIM) ? acc[r][c] : -INFINITY;
        ins3(v, gh, v0, v1, v2, i0, i1, i2);
      }
#pragma unroll
      for (int s = 0; s < 2; ++s) {
        const int off = 16 << s;
        float ov0 = __shfl_down(v0, off);
        float ov1 = __shfl_down(v1, off);
        float ov2 = __shfl_down(v2, off);
        int   oi0 = __shfl_down(i0, off);
        int   oi1 = __shfl_down(i1, off);
        int   oi2 = __shfl_down(i2, off);
        ins3(ov0, oi0, v0, v1, v2, i0, i1, i2);
        ins3(ov1, oi1, v0, v1, v2, i0, i1, i2);
        ins3(ov2, oi2, v0, v1, v2, i0, i1, i2);
      }
      if ((ty & 3) == 0) {
        mv[(wvi * BN + col) * 3 + 0] = v0;
        mv[(wvi * BN + col) * 3 + 1] = v1;
        mv[(wvi * BN + col) * 3 + 2] = v2;
        mi[(wvi * BN + col) * 3 + 0] = i0;
        mi[(wvi * BN + col) * 3 + 1] = i1;
        mi[(wvi * BN + col) * 3 + 2] = i2;
      }
    }
    __syncthreads();
    // threads 0..127 own one column; merge 4 wave-lists (ascending h bands)
    if (tid < BN) {
#pragma unroll
      for (int w = 0; w < 4; ++w)
#pragma unroll
        for (int j = 0; j < 3; ++j) {
          float v = mv[(w * BN + tid) * 3 + j];
          int   i = mi[(w * BN + tid) * 3 + j];
          ins3(v, i, gv0, gv1, gv2, gi0, gi1, gi2);
        }
    }
  }

  if (tid < BN) {
    int t = t0 + tid;
    if (t < T_DIM) {
      size_t base = ((size_t)(bc * nsplit + sp) * KTOP) * T_DIM + t;
      wv[base]             = gv0;
      wv[base + T_DIM]     = gv1;
      wv[base + 2 * T_DIM] = gv2;
      wi[base]             = gi0;
      wi[base + T_DIM]     = gi1;
      wi[base + 2 * T_DIM] = gi2;
    }
  }
}

// K3: merge the nsplit partial top-3 lists, causal-pool the indices, gather
// harmonic_loc rows, sum over K, threshold, write (B,C,F,T) coalesced.
__global__ __launch_bounds__(256, 4)
void hi_k3_pool_gather(const float* __restrict__ wv, const int* __restrict__ wi,
                       const float* __restrict__ hl, float* __restrict__ out,
                       int nsplit) {
  const int tid = threadIdx.x;
  const int t0 = blockIdx.x * 64;
  const int bc = blockIdx.y;

  __shared__ float pos_lds[66 * KTOP];   // t0-2 .. t0+63
  __shared__ int   rows[64 * KTOP];
  __shared__ float S[64 * 65];           // [t_local][f_chunk] transpose buffer

  if (tid < 66) {
    int t = t0 - 2 + tid;
    float p0 = PADV, p1 = PADV, p2 = PADV;
    if (t >= 0 && t < T_DIM) {
      float v0 = -INFINITY, v1 = -INFINITY, v2 = -INFINITY;
      int i0 = 0, i1 = 0, i2 = 0;
      for (int sp = 0; sp < nsplit; ++sp)        // ascending h ranges
        for (int j = 0; j < KTOP; ++j) {         // descending values
          size_t idx = ((size_t)(bc * nsplit + sp) * KTOP + j) * T_DIM + t;
          ins3(wv[idx], wi[idx], v0, v1, v2, i0, i1, i2);
        }
      p0 = (float)i0; p1 = (float)i1; p2 = (float)i2;
    }
    pos_lds[tid * KTOP + 0] = p0;
    pos_lds[tid * KTOP + 1] = p1;
    pos_lds[tid * KTOP + 2] = p2;
  }
  __syncthreads();
  if (tid < 64) {
#pragma unroll
    for (int k = 0; k < KTOP; ++k) {
      float s = (pos_lds[tid * KTOP + k] + pos_lds[(tid + 1) * KTOP + k])
                + pos_lds[(tid + 2) * KTOP + k];
      rows[tid * KTOP + k] = (int)(s / 3.0f);   // matches ref fp32 /3 + int cast
    }
  }
  __syncthreads();

  const int w = tid >> 6, lane = tid & 63;
  for (int fc = 0; fc < 6; ++fc) {
    const int f0 = fc * 64;
    for (int i = 0; i < 16; ++i) {
      int tl = w * 16 + i;
      int r0 = rows[tl * KTOP + 0];
      int r1 = rows[tl * KTOP + 1];
      int r2 = rows[tl * KTOP + 2];
      int f = f0 + lane;
      float s = 0.f;
      if (f < F_DIM)
        s = (hl[(size_t)r0 * F_DIM + f] + hl[(size_t)r1 * F_DIM + f])
            + hl[(size_t)r2 * F_DIM + f];
      S[tl * 65 + lane] = s;
    }
    __syncthreads();
#pragma unroll
    for (int i = 0; i < 16; ++i) {
      int e = tid + 256 * i;
      int fl = e >> 6, tl = e & 63;
      int f = f0 + fl, t = t0 + tl;
      if (f < F_DIM && t < T_DIM)
        out[((size_t)bc * F_DIM + f) * T_DIM + t] = (S[tl * 65 + fl] > 0.f) ? 1.f : 0.f;
    }
    __syncthreads();
  }
}

extern "C" void kernel_launch(void* const* d_in, const int* in_sizes, int n_in,
                              void* d_out, int out_size, void* d_ws, size_t ws_size,
                              hipStream_t stream) {
  const float* mag = (const float*)d_in[0];   // (8,2,321,1000)
  const float* im  = (const float*)d_in[1];   // (4200,321)
  const float* hl  = (const float*)d_in[2];   // (4200,321)
  float* out = (float*)d_out;                 // (8,2,321,1000)

  // nsplit=8 needs 16*8*3*1000*8B = 3.07 MB of ws; fall back to 4 if tight.
  int nsplit = (ws_size >= (size_t)NBC * 8 * KTOP * T_DIM * 8) ? 8 : 4;
  float* wv = (float*)d_ws;
  int*   wi = (int*)d_ws + (size_t)NBC * nsplit * KTOP * T_DIM;

  dim3 g1((T_DIM + BN - 1) / BN, NBC, nsplit);   // 8 x 16 x 8 = 1024 blocks
  hipLaunchKernelGGL(hi_k1_gemm_top3, g1, dim3(256), 0, stream, mag, im, wv, wi, nsplit);

  dim3 g3((T_DIM + 63) / 64, NBC);               // 16 x 16 = 256 blocks
  hipLaunchKernelGGL(hi_k3_pool_gather, g3, dim3(256), 0, stream, wv, wi, hl, out, nsplit);
}

// Round 12
// 982.954 us; speedup vs baseline: 1.3301x; 1.3301x over previous
//
#include <hip/hip_runtime.h>
#include <math.h>

// Problem constants
#define F_DIM 321
#define H_DIM 4200
#define T_DIM 1000
#define NBC   16      // B*C = 8*2
#define KTOP  3
#define PADV  1e-8f
#define NSPLIT 4

// GEMM tiling
#define BM 128        // h rows per block tile
#define BN 128        // t cols per block tile
#define BK 32
#define LDA 32        // linear A rows; XOR swizzle applied on write AND read
#define LDB 128       // linear B rows (reads are 2 words/bank max)
#define NHT 33        // ceil(H_DIM / BM)
#define NKT 10        // k-tiles of 32 covering k=0..319 (tail k=320 separate)

typedef float v4f __attribute__((ext_vector_type(4)));

__device__ __forceinline__ void ins3(float v, int i,
                                     float& v0, float& v1, float& v2,
                                     int& i0, int& i1, int& i2) {
  // strict '>' keeps earlier (smaller-h) entries ahead on ties == lax.top_k
  if (v > v0)      { v2 = v1; i2 = i1; v1 = v0; i1 = i0; v0 = v; i0 = i; }
  else if (v > v1) { v2 = v1; i2 = i1; v1 = v;  i1 = i; }
  else if (v > v2) { v2 = v;  i2 = i; }
}

// K1: fused fp32 GEMM (nominee = integral_m @ mag[bc]) + running top-3 over h.
// T3-min prefetch pipeline (reg-staged): per kt, next tile's global loads are
// ISSUED before compute, ds_written after compute, one barrier per kt ->
// HBM latency hides under the 4096-cyc FMA phase (fixes the 2-phase stall
// that capped VALUBusy at ~26% in r4-r10). Double-buffered LDS, 2 blocks/CU
// (LDS-bound), waves_per_eu(2,2) grants the full 256-reg budget -> no spill.
__global__ __launch_bounds__(256)
__attribute__((amdgpu_waves_per_eu(2, 2)))
void hi_k1_gemm_top3(const float* __restrict__ mag,
                     const float* __restrict__ im,
                     float* __restrict__ wv, int* __restrict__ wi) {
  const int tid = threadIdx.x;
  const int tx = tid & 15;
  const int ty = tid >> 4;        // 16 row-groups of 8
  const int th = tid >> 5;        // 0..7 (staging row-within-round)
  const int kq = tid & 31;        // staging k (A) / t-quad (B)
  const int t0 = blockIdx.x * BN;
  const int bc = blockIdx.y;
  const int sp = blockIdx.z;
  const int ht_begin = (sp * NHT) / NSPLIT;
  const int ht_end   = ((sp + 1) * NHT) / NSPLIT;
  const int row0 = ty * 8;
  const int xsw = (ty & 3) << 2;  // A bank swizzle for this thread's rows
  const int wvi = tid >> 6;       // wave index 0..3

  __shared__ __align__(16) float As[2][BM * LDA];  // [h][k^swz], dbuf
  __shared__ __align__(16) float Bs[2][BK * LDB];  // [k][t], dbuf
  __shared__ float mv[4 * BN * KTOP];              // merge scratch (separate)
  __shared__ int   mi[4 * BN * KTOP];

  const float* magbc = mag + (size_t)bc * F_DIM * T_DIM;

  float ar[16];   // staged A (one word per round)
  v4f   br[4];    // staged B (one v4f per round)

  // issue global loads for tile (nh0, nk0) into registers (no waiting)
  auto gload = [&](int nh0, int nk0) {
#pragma unroll
    for (int l = 0; l < 16; ++l) {
      int gh = nh0 + th + 8 * l;
      gh = (gh < H_DIM) ? gh : (H_DIM - 1);   // clamp: dup row, masked later
      ar[l] = im[(size_t)gh * F_DIM + nk0 + kq];
    }
#pragma unroll
    for (int l = 0; l < 4; ++l)
      // t-overrun of last tile reads next k-row (in-bounds garbage, masked)
      br[l] = *(const v4f*)(magbc + (size_t)(nk0 + th + 8 * l) * T_DIM + t0 + 4 * kq);
  };
  // write staged regs into LDS buffer `buf` (compiler inserts vmcnt waits)
  auto dswrite = [&](int buf) {
#pragma unroll
    for (int l = 0; l < 16; ++l)
      As[buf][(th + 8 * l) * LDA + (kq ^ ((l & 3) << 2))] = ar[l];
#pragma unroll
    for (int l = 0; l < 4; ++l)
      *(v4f*)(&Bs[buf][(th + 8 * l) * LDB + 4 * kq]) = br[l];
  };

  float gv0 = -INFINITY, gv1 = -INFINITY, gv2 = -INFINITY;
  int   gi0 = 0, gi1 = 0, gi2 = 0;

  int cur = 0;
  gload(ht_begin * BM, 0);
  dswrite(0);
  __syncthreads();

  for (int ht = ht_begin; ht < ht_end; ++ht) {
    const int h0 = ht * BM;
    float acc[8][8];
#pragma unroll
    for (int r = 0; r < 8; ++r)
#pragma unroll
      for (int c = 0; c < 8; ++c) acc[r][c] = 0.f;

    for (int kt = 0; kt < NKT; ++kt) {
      // 1) issue next tile's global loads (this ht's kt+1, or next ht's kt 0)
      bool have_next = true;
      int nh0 = h0, nk0 = (kt + 1) * BK;
      if (kt == NKT - 1) {
        if (ht + 1 < ht_end) { nh0 = h0 + BM; nk0 = 0; }
        else have_next = false;
      }
      if (have_next) gload(nh0, nk0);

      // 2) compute current buffer: 8 groups of 4 k
#pragma unroll 1
      for (int g = 0; g < 8; ++g) {
        v4f Bv[8];
#pragma unroll
        for (int kk = 0; kk < 4; ++kk) {
          Bv[kk * 2]     = *(const v4f*)(&Bs[cur][(g * 4 + kk) * LDB + tx * 4]);
          Bv[kk * 2 + 1] = *(const v4f*)(&Bs[cur][(g * 4 + kk) * LDB + 64 + tx * 4]);
        }
#pragma unroll
        for (int r = 0; r < 8; ++r) {
          const v4f Ar = *(const v4f*)(&As[cur][(row0 + r) * LDA + ((g * 4) ^ xsw)]);
#pragma unroll
          for (int kk = 0; kk < 4; ++kk)
#pragma unroll
            for (int c = 0; c < 4; ++c) {
              acc[r][c]     = fmaf(Ar[kk], Bv[kk * 2][c],     acc[r][c]);
              acc[r][c + 4] = fmaf(Ar[kk], Bv[kk * 2 + 1][c], acc[r][c + 4]);
            }
        }
      }

      // 3) land staged tile in the other buffer; 4) one barrier per kt
      if (have_next) dswrite(cur ^ 1);
      __syncthreads();
      cur ^= 1;
    }

    // K tail: k = 320 (single column), straight from global (L2-resident)
    {
      float bt[8];
#pragma unroll
      for (int c = 0; c < 8; ++c) {
        int gt = t0 + ((c < 4) ? (tx * 4 + c) : (64 + tx * 4 + c - 4));
        bt[c] = (gt < T_DIM) ? magbc[(size_t)(F_DIM - 1) * T_DIM + gt] : 0.f;
      }
#pragma unroll
      for (int r = 0; r < 8; ++r) {
        int gh = h0 + row0 + r;
        float a = (gh < H_DIM) ? im[(size_t)gh * F_DIM + (F_DIM - 1)] : 0.f;
#pragma unroll
        for (int c = 0; c < 8; ++c) acc[r][c] = fmaf(a, bt[c], acc[r][c]);
      }
    }

    // per-column top-3 over own 8 rows (h ascending), then merge the 4
    // ty-bands in each wave (shfl_down 16 then 32 keeps ascending-h order)
#pragma unroll
    for (int c = 0; c < 8; ++c) {
      const int col = (c < 4) ? (tx * 4 + c) : (64 + tx * 4 + c - 4);
      float v0 = -INFINITY, v1 = -INFINITY, v2 = -INFINITY;
      int   i0 = 0, i1 = 0, i2 = 0;
#pragma unroll
      for (int r = 0; r < 8; ++r) {
        int gh = h0 + row0 + r;
        float v = (gh < H_DIM) ? acc[r][c] : -INFINITY;
        ins3(v, gh, v0, v1, v2, i0, i1, i2);
      }
#pragma unroll
      for (int s = 0; s < 2; ++s) {
        const int off = 16 << s;
        float ov0 = __shfl_down(v0, off);
        float ov1 = __shfl_down(v1, off);
        float ov2 = __shfl_down(v2, off);
        int   oi0 = __shfl_down(i0, off);
        int   oi1 = __shfl_down(i1, off);
        int   oi2 = __shfl_down(i2, off);
        ins3(ov0, oi0, v0, v1, v2, i0, i1, i2);
        ins3(ov1, oi1, v0, v1, v2, i0, i1, i2);
        ins3(ov2, oi2, v0, v1, v2, i0, i1, i2);
      }
      if ((ty & 3) == 0) {
        mv[(wvi * BN + col) * 3 + 0] = v0;
        mv[(wvi * BN + col) * 3 + 1] = v1;
        mv[(wvi * BN + col) * 3 + 2] = v2;
        mi[(wvi * BN + col) * 3 + 0] = i0;
        mi[(wvi * BN + col) * 3 + 1] = i1;
        mi[(wvi * BN + col) * 3 + 2] = i2;
      }
    }
    __syncthreads();
    // threads 0..127 own one column; merge 4 wave-lists (ascending h bands)
    if (tid < BN) {
#pragma unroll
      for (int w = 0; w < 4; ++w)
#pragma unroll
        for (int j = 0; j < 3; ++j) {
          float v = mv[(w * BN + tid) * 3 + j];
          int   i = mi[(w * BN + tid) * 3 + j];
          ins3(v, i, gv0, gv1, gv2, gi0, gi1, gi2);
        }
    }
  }

  if (tid < BN) {
    int t = t0 + tid;
    if (t < T_DIM) {
      size_t base = ((size_t)(bc * NSPLIT + sp) * KTOP) * T_DIM + t;
      wv[base]             = gv0;
      wv[base + T_DIM]     = gv1;
      wv[base + 2 * T_DIM] = gv2;
      wi[base]             = gi0;
      wi[base + T_DIM]     = gi1;
      wi[base + 2 * T_DIM] = gi2;
    }
  }
}

// K3: merge the NSPLIT partial top-3 lists, causal-pool the indices, gather
// harmonic_loc rows, sum over K, threshold, write (B,C,F,T) coalesced.
__global__ __launch_bounds__(256, 4)
void hi_k3_pool_gather(const float* __restrict__ wv, const int* __restrict__ wi,
                       const float* __restrict__ hl, float* __restrict__ out) {
  const int tid = threadIdx.x;
  const int t0 = blockIdx.x * 64;
  const int bc = blockIdx.y;

  __shared__ float pos_lds[66 * KTOP];   // t0-2 .. t0+63
  __shared__ int   rows[64 * KTOP];
  __shared__ float S[64 * 65];           // [t_local][f_chunk] transpose buffer

  if (tid < 66) {
    int t = t0 - 2 + tid;
    float p0 = PADV, p1 = PADV, p2 = PADV;
    if (t >= 0 && t < T_DIM) {
      float v0 = -INFINITY, v1 = -INFINITY, v2 = -INFINITY;
      int i0 = 0, i1 = 0, i2 = 0;
      for (int sp = 0; sp < NSPLIT; ++sp)        // ascending h ranges
        for (int j = 0; j < KTOP; ++j) {         // descending values
          size_t idx = ((size_t)(bc * NSPLIT + sp) * KTOP + j) * T_DIM + t;
          ins3(wv[idx], wi[idx], v0, v1, v2, i0, i1, i2);
        }
      p0 = (float)i0; p1 = (float)i1; p2 = (float)i2;
    }
    pos_lds[tid * KTOP + 0] = p0;
    pos_lds[tid * KTOP + 1] = p1;
    pos_lds[tid * KTOP + 2] = p2;
  }
  __syncthreads();
  if (tid < 64) {
#pragma unroll
    for (int k = 0; k < KTOP; ++k) {
      float s = (pos_lds[tid * KTOP + k] + pos_lds[(tid + 1) * KTOP + k])
                + pos_lds[(tid + 2) * KTOP + k];
      rows[tid * KTOP + k] = (int)(s / 3.0f);   // matches ref fp32 /3 + int cast
    }
  }
  __syncthreads();

  const int w = tid >> 6, lane = tid & 63;
  for (int fc = 0; fc < 6; ++fc) {
    const int f0 = fc * 64;
    for (int i = 0; i < 16; ++i) {
      int tl = w * 16 + i;
      int r0 = rows[tl * KTOP + 0];
      int r1 = rows[tl * KTOP + 1];
      int r2 = rows[tl * KTOP + 2];
      int f = f0 + lane;
      float s = 0.f;
      if (f < F_DIM)
        s = (hl[(size_t)r0 * F_DIM + f] + hl[(size_t)r1 * F_DIM + f])
            + hl[(size_t)r2 * F_DIM + f];
      S[tl * 65 + lane] = s;
    }
    __syncthreads();
#pragma unroll
    for (int i = 0; i < 16; ++i) {
      int e = tid + 256 * i;
      int fl = e >> 6, tl = e & 63;
      int f = f0 + fl, t = t0 + tl;
      if (f < F_DIM && t < T_DIM)
        out[((size_t)bc * F_DIM + f) * T_DIM + t] = (S[tl * 65 + fl] > 0.f) ? 1.f : 0.f;
    }
    __syncthreads();
  }
}

extern "C" void kernel_launch(void* const* d_in, const int* in_sizes, int n_in,
                              void* d_out, int out_size, void* d_ws, size_t ws_size,
                              hipStream_t stream) {
  const float* mag = (const float*)d_in[0];   // (8,2,321,1000)
  const float* im  = (const float*)d_in[1];   // (4200,321)
  const float* hl  = (const float*)d_in[2];   // (4200,321)
  float* out = (float*)d_out;                 // (8,2,321,1000)

  // ws layout: wv [16][NSPLIT][3][1000] floats, then wi same in ints (~1.5 MB)
  float* wv = (float*)d_ws;
  int*   wi = (int*)d_ws + (size_t)NBC * NSPLIT * KTOP * T_DIM;

  dim3 g1((T_DIM + BN - 1) / BN, NBC, NSPLIT);   // 8 x 16 x 4 = 512 blocks
  hipLaunchKernelGGL(hi_k1_gemm_top3, g1, dim3(256), 0, stream, mag, im, wv, wi);

  dim3 g3((T_DIM + 63) / 64, NBC);               // 16 x 16 = 256 blocks
  hipLaunchKernelGGL(hi_k3_pool_gather, g3, dim3(256), 0, stream, wv, wi, hl, out);
}